// Round 9
// baseline (2916.324 us; speedup 1.0000x reference)
//
#include <hip/hip_runtime.h>
#include <math.h>

// ---------------------------------------------------------------------------
// DelayRNN persistent kernel, R9: spread LDS-bound dots over more CUs.
// R8 post-mortem: savings matched LDS-byte arithmetic at 2.4GHz => dots are
// LDS-BW-bound per CU (85 B/cy ds_read_b128). R9: GRU 32->64 blocks (4 cols
// each, k-split 8) halves per-block stream (458KB, ~2.2us); DG retiled
// (c8,b4,kq8, 1.5B/FMA, 490KB, ~2.4us). Blocks: 64 GRU | 32 E1 | 16 F1 |
// 8 F2 | 1 DG = 121. All else from R8 (sc1 protocol, tree barrier, pipeline).
// ---------------------------------------------------------------------------

#define kB 32
#define kT 128
#define kI 64
#define kH 256
#define kD 32
#define kC 64
#define kOut 32
#define kSteps (kT + kOut)            // 160
#define NB 121
#define NTHR 256
#define NT_ALL (NB * NTHR)
#define BPG 16
#define NGRP 8

// ws float offsets. Zeroed region: [0, WS_NZ)
#define WS_H     384                   // h[2][32][256]
#define WS_CORR  (WS_H + 2*8192)       // corr[2][32][256]
#define WS_MEM   (WS_CORR + 2*8192)    // mem events [32][160][64]
#define WS_NZ    (WS_MEM + kB*kSteps*kI)
#define WS_LIN   WS_NZ                 // lin[2][32][256] (pre-elu e1 out)
#define WS_O1    (WS_LIN + 2*8192)     // o1[2][32][256]
#define WS_W2    (WS_O1 + 2*8192)      // W2 = W_e2@W_ih [256][768]
#define WS_B2    (WS_W2 + kH*3*kH)     // B2 [768]
#define WS_G     (WS_B2 + 3*kH)        // gumbel [T*B*D]
#define WS_ZERO_BYTES ((size_t)WS_NZ * sizeof(float))

// ---- coherent scalar access (agent scope, L3 coherence point) ----
__device__ __forceinline__ float cload(const float* p) {
  return __hip_atomic_load(p, __ATOMIC_RELAXED, __HIP_MEMORY_SCOPE_AGENT);
}
__device__ __forceinline__ void cstore(float* p, float v) {
  __hip_atomic_store(p, v, __ATOMIC_RELAXED, __HIP_MEMORY_SCOPE_AGENT);
}
__device__ __forceinline__ float4 cload4(const float* p) {
  float4 r;
  asm volatile("global_load_dwordx4 %0, %1, off sc0 sc1" : "=v"(r) : "v"(p));
  return r;
}
__device__ __forceinline__ void waitvm() {
  asm volatile("s_waitcnt vmcnt(0)" ::: "memory");
}

// ---- Threefry-2x32 (jax partitionable path) ----
__device__ __forceinline__ void tf2x32(unsigned k0, unsigned k1,
                                       unsigned x0, unsigned x1,
                                       unsigned& o0, unsigned& o1) {
  unsigned ks2 = k0 ^ k1 ^ 0x1BD11BDAu;
  unsigned v0 = x0 + k0, v1 = x1 + k1;
#define TFR(r) { v0 += v1; v1 = (v1 << (r)) | (v1 >> (32-(r))); v1 ^= v0; }
  TFR(13) TFR(15) TFR(26) TFR(6)   v0 += k1;  v1 += ks2 + 1u;
  TFR(17) TFR(29) TFR(16) TFR(24)  v0 += ks2; v1 += k0  + 2u;
  TFR(13) TFR(15) TFR(26) TFR(6)   v0 += k0;  v1 += k1  + 3u;
  TFR(17) TFR(29) TFR(16) TFR(24)  v0 += k1;  v1 += ks2 + 4u;
  TFR(13) TFR(15) TFR(26) TFR(6)   v0 += ks2; v1 += k0  + 5u;
#undef TFR
  o0 = v0; o1 = v1;
}
__device__ __forceinline__ float bits_to_gumbel(unsigned bits) {
  float f = __uint_as_float((bits >> 9) | 0x3F800000u) - 1.0f;
  float u = f + 1.17549435e-38f;
  return -logf(-logf(u));
}

__device__ __forceinline__ void gridbar_full(unsigned* u, unsigned target) {
  __syncthreads();
  if (threadIdx.x == 0) {
    __threadfence();
    __hip_atomic_fetch_add(&u[320], 1u, __ATOMIC_ACQ_REL, __HIP_MEMORY_SCOPE_AGENT);
    while (__hip_atomic_load(&u[320], __ATOMIC_RELAXED, __HIP_MEMORY_SCOPE_AGENT) < target)
      __builtin_amdgcn_s_sleep(1);
    __threadfence();
  }
  __syncthreads();
}
__device__ __forceinline__ void gridbar_nf(unsigned* u, unsigned nround,
                                           int grp, int gsz) {
  asm volatile("s_waitcnt vmcnt(0) lgkmcnt(0)" ::: "memory");
  __syncthreads();
  if (threadIdx.x == 0) {
    unsigned old = __hip_atomic_fetch_add(&u[grp * 32], 1u,
                      __ATOMIC_RELAXED, __HIP_MEMORY_SCOPE_AGENT);
    if (old + 1u == (unsigned)gsz * nround) {
      unsigned r = __hip_atomic_fetch_add(&u[256], 1u,
                      __ATOMIC_RELAXED, __HIP_MEMORY_SCOPE_AGENT);
      if (r + 1u == NGRP * nround)
        __hip_atomic_store(&u[288], nround, __ATOMIC_RELAXED, __HIP_MEMORY_SCOPE_AGENT);
    }
    while (__hip_atomic_load(&u[288], __ATOMIC_RELAXED, __HIP_MEMORY_SCOPE_AGENT) < nround)
      __builtin_amdgcn_s_sleep(2);
    asm volatile("" ::: "memory");
  }
  __syncthreads();
}

__device__ __forceinline__ float elu1(float v) { return v > 0.f ? v : expm1f(v); }

__global__ __launch_bounds__(NTHR)
void delay_rnn(const float* __restrict__ x, const int* __restrict__ lengths,
               const float* __restrict__ W_dg1, const float* __restrict__ b_dg1,
               const float* __restrict__ W_dg2, const float* __restrict__ b_dg2,
               const float* __restrict__ W_e1,  const float* __restrict__ b_e1,
               const float* __restrict__ W_e2,  const float* __restrict__ b_e2,
               const float* __restrict__ W_ih,  const float* __restrict__ b_ih,
               const float* __restrict__ W_hh,  const float* __restrict__ b_hh,
               const float* __restrict__ W_f1,  const float* __restrict__ b_f1,
               const float* __restrict__ W_f2,  const float* __restrict__ b_f2,
               float* __restrict__ out, float* __restrict__ ws) {
  const int tid = threadIdx.x;
  const int bid = blockIdx.x;
  const int gid = bid * NTHR + tid;
  const int grp = bid / BPG;                       // 0..7 (bid 112..120 -> 7)
  const int gsz = (grp == NGRP - 1) ? (NB - (NGRP - 1) * BPG) : BPG;

  unsigned* baru = (unsigned*)ws;
  float* hBuf  = ws + WS_H;
  float* corrB = ws + WS_CORR;
  float* mem   = ws + WS_MEM;
  float* linB  = ws + WS_LIN;
  float* o1B   = ws + WS_O1;
  float* W2g   = ws + WS_W2;
  float* B2g   = ws + WS_B2;
  float* g     = ws + WS_G;

  __shared__ float S[31104];           // role-carved (max: DG)
  __shared__ float lgarr[1056];
  __shared__ float sb1[32], sb2[32], dec_sh[32];
  __shared__ int   sel[32], len_s[32];

  // ---------------- init: gumbel, W2 = W_e2@W_ih, B2 ----------------
  {
    unsigned k0, k1;
    tf2x32(0u, 42u, 0u, 0u, k0, k1);
    for (int i = gid; i < kT * kB * kD; i += NT_ALL) {
      unsigned a, b;
      tf2x32(k0, k1, 0u, (unsigned)i, a, b);
      g[i] = bits_to_gumbel(a ^ b);
    }
  }
  for (int idx = gid; idx < kH * 3 * kH; idx += NT_ALL) {
    int k = idx / (3 * kH), n = idx % (3 * kH);
    const float* wr = W_e2 + k * kH;
    float s0 = 0, s1 = 0, s2 = 0, s3 = 0;
    for (int m = 0; m < kH; m += 4) {
      float4 wv = *(const float4*)(wr + m);
      s0 += wv.x * W_ih[(m    ) * 3 * kH + n];
      s1 += wv.y * W_ih[(m + 1) * 3 * kH + n];
      s2 += wv.z * W_ih[(m + 2) * 3 * kH + n];
      s3 += wv.w * W_ih[(m + 3) * 3 * kH + n];
    }
    W2g[idx] = ((s0 + s1) + (s2 + s3));
  }
  for (int n = gid; n < 3 * kH; n += NT_ALL) {
    float s = b_ih[n];
    for (int m = 0; m < kH; ++m) s += b_e2[m] * W_ih[m * 3 * kH + n];
    B2g[n] = s;
  }

  gridbar_full(baru, NB);

  // ---------------- persistent LDS weight staging ----------------
  if (bid < 64) {                                   // GRU: 4 cols each
    float* whh = S; float* w2 = S + 3120;           // [12][260] each
    const int jb = bid * 4;
    for (int i = tid; i < 3072; i += NTHR) {
      int gg = i >> 10, r = i & 1023, jj = r >> 8, k = r & 255;
      whh[(gg * 4 + jj) * 260 + k] = W_hh[k * 768 + gg * 256 + jb + jj];
      w2 [(gg * 4 + jj) * 260 + k] = W2g [k * 768 + gg * 256 + jb + jj];
    }
    if (tid < 12) { int gg = tid >> 2, jj = tid & 3;
      sb1[tid] = b_hh[gg * 256 + jb + jj];
      sb2[tid] = B2g [gg * 256 + jb + jj];
    }
    if (tid < 32) len_s[tid] = lengths[tid];
  } else if (bid < 96) {                            // E1 + lin_0
    float* we1 = S;
    const int jb = (bid - 64) * 8;
    for (int i = tid; i < 1024; i += NTHR) {
      int jj = i >> 7, k = i & 127;
      we1[jj * 132 + k] = W_e1[k * 256 + jb + jj];
    }
    if (tid < 8) sb1[tid] = b_e1[jb + tid];
    __syncthreads();
    { int b = tid >> 3, jj = tid & 7;               // lin_0 = x_0@We1[:64]+b
      const float* xr = x + (b * kT) * kI;
      float a0 = 0, a1 = 0, a2 = 0, a3 = 0;
      for (int k = 0; k < 64; k += 4) {
        float4 xv = *(const float4*)(xr + k);
        a0 += xv.x * we1[jj * 132 + k];
        a1 += xv.y * we1[jj * 132 + k + 1];
        a2 += xv.z * we1[jj * 132 + k + 2];
        a3 += xv.w * we1[jj * 132 + k + 3];
      }
      cstore(&linB[b * 256 + jb + jj], ((a0 + a1) + (a2 + a3)) + sb1[jj]);
    }
  } else if (bid < 112) {                           // F1
    float* wf1 = S;
    const int jb = (bid - 96) * 16;
    for (int i = tid; i < 4096; i += NTHR) {
      int jj = i >> 8, k = i & 255;
      wf1[jj * 260 + k] = W_f1[k * 256 + jb + jj];
    }
    if (tid < 16) sb1[tid] = b_f1[jb + tid];
  } else if (bid < 120) {                           // F2
    float* wf2 = S;
    const int cb = (bid - 112) * 8;
    for (int i = tid; i < 2048; i += NTHR) {
      int cc = i >> 8, k = i & 255;
      wf2[cc * 260 + k] = W_f2[k * 64 + cb + cc];
    }
    if (tid < 8) sb2[tid] = b_f2[cb + tid];
  } else {                                          // DG
    float* wdg1 = S; float* wdg2 = S + 10368;
    for (int i = tid; i < 10240; i += NTHR) {
      int j = i / 320, k = i % 320;
      wdg1[j * 324 + k] = W_dg1[k * 32 + j];
    }
    for (int i = tid; i < 1024; i += NTHR) wdg2[i] = W_dg2[i];
    if (tid < 32) { sb1[tid] = b_dg1[tid]; sb2[tid] = b_dg2[tid];
                    dec_sh[tid] = powf(0.99f, (float)(tid + 1)); }
  }

  unsigned nr = 1;
  gridbar_nf(baru, nr, grp, gsz); nr++;

  // ---------------- time loop: ONE barrier per phase ----------------
  for (int s = 0; s <= kSteps + 1; ++s) {
    if (bid < 64) {
      // ===== GRU (+inline gh): 4 cols, tile 4b x 1c x 6g, k-split 8 =====
      if (s < kSteps) {
        float* whh = S; float* w2 = S + 3120;
        float* sH = S + 6240; float* sLin = S + 14560;
        float* red = S + 22880;                     // [768][8]
        const float* hR = hBuf + (s & 1) * 8192;
        const float* lR = linB + (s & 1) * 8192;
        const float* cR = corrB + (s & 1) * 8192;
        float4 th[8], tl[8], tc[8];
        #pragma unroll
        for (int u8 = 0; u8 < 8; ++u8) {
          int i4 = (tid + u8 * 256) * 4;
          th[u8] = cload4(hR + i4);
          tl[u8] = cload4(lR + i4);
        }
        if (s < kT) {
          #pragma unroll
          for (int u8 = 0; u8 < 8; ++u8) tc[u8] = cload4(cR + (tid + u8 * 256) * 4);
        } else {
          #pragma unroll
          for (int u8 = 0; u8 < 8; ++u8) tc[u8] = make_float4(0.f, 0.f, 0.f, 0.f);
        }
        waitvm();
        #pragma unroll
        for (int u8 = 0; u8 < 8; ++u8) {
          int idx = tid + u8 * 256; int b = idx >> 6, k4 = idx & 63;
          *(float4*)&sH[b * 260 + k4 * 4] = th[u8];
          float4 v;
          v.x = elu1(tl[u8].x + tc[u8].x);
          v.y = elu1(tl[u8].y + tc[u8].y);
          v.z = elu1(tl[u8].z + tc[u8].z);
          v.w = elu1(tl[u8].w + tc[u8].w);
          *(float4*)&sLin[b * 260 + k4 * 4] = v;
        }
        __syncthreads();
        const float4* sH4 = (const float4*)sH;
        const float4* sL4 = (const float4*)sLin;
        const float4* wh4 = (const float4*)whh;
        const float4* w24 = (const float4*)w2;
        const int c  = tid & 3;
        const int b4 = (tid >> 2) & 7;
        const int kq = tid >> 5;                    // 0..7, k-chunk 32
        float acc[24];
        #pragma unroll
        for (int a = 0; a < 24; ++a) acc[a] = 0.f;
        for (int kk = 0; kk < 8; ++kk) {
          int k4 = kq * 8 + kk;
          float4 wr[6];
          #pragma unroll
          for (int gg = 0; gg < 3; ++gg) {
            wr[gg]     = wh4[(gg * 4 + c) * 65 + k4];
            wr[3 + gg] = w24[(gg * 4 + c) * 65 + k4];
          }
          #pragma unroll
          for (int bi = 0; bi < 4; ++bi) {
            int b = bi * 8 + b4;
            float4 h4 = sH4[b * 65 + k4];
            float4 l4 = sL4[b * 65 + k4];
            #pragma unroll
            for (int gg = 0; gg < 3; ++gg) {
              float4 w = wr[gg];
              acc[bi * 6 + gg]     += h4.x * w.x + h4.y * w.y + h4.z * w.z + h4.w * w.w;
              w = wr[3 + gg];
              acc[bi * 6 + 3 + gg] += l4.x * w.x + l4.y * w.y + l4.z * w.z + l4.w * w.w;
            }
          }
        }
        #pragma unroll
        for (int bi = 0; bi < 4; ++bi)
          #pragma unroll
          for (int rr = 0; rr < 6; ++rr) {
            int o = ((bi * 8 + b4) * 4 + c) * 6 + rr;
            red[o * 8 + kq] = acc[bi * 6 + rr];
          }
        __syncthreads();
        if (tid < 128) {  // epilogue: thread -> (b, col)
          int b = tid >> 2, cc = tid & 3, jg = bid * 4 + cc;
          int ob = (b * 4 + cc) * 6;
          float dots[6];
          #pragma unroll
          for (int rr = 0; rr < 6; ++rr) {
            float4 v0 = *(const float4*)&red[(ob + rr) * 8];
            float4 v1 = *(const float4*)&red[(ob + rr) * 8 + 4];
            dots[rr] = ((v0.x + v0.y) + (v0.z + v0.w)) +
                       ((v1.x + v1.y) + (v1.z + v1.w));
          }
          float ghr = dots[0] + sb1[cc];
          float ghz = dots[1] + sb1[4 + cc];
          float ghn = dots[2] + sb1[8 + cc];
          float gir = dots[3] + sb2[cc];
          float giz = dots[4] + sb2[4 + cc];
          float gin = dots[5] + sb2[8 + cc];
          float r = 1.f / (1.f + expf(-(gir + ghr)));
          float z = 1.f / (1.f + expf(-(giz + ghz)));
          float n = tanhf(gin + r * ghn);
          float hold = sH[b * 260 + jg];
          float nh = (1.f - z) * n + z * hold;
          float hv = (s < kT) ? ((s < len_s[b]) ? nh : hold) : nh;
          cstore(&hBuf[((s + 1) & 1) * 8192 + b * 256 + jg], hv);
        }
      }
    } else if (bid < 96) {
      // ===== E1: lin_{s+1} (pre-elu) =====
      if (s <= kSteps - 2) {
        float* we1 = S; float* sx = S + 1056; float* sm = S + 3232;
        const int jb = (bid - 64) * 8;
        const bool encx = (s + 1 < kT);
        float4 tm[2];
        #pragma unroll
        for (int u2 = 0; u2 < 2; ++u2) {
          int idx = tid + u2 * 256; int b = idx >> 4, k4 = idx & 15;
          tm[u2] = cload4(mem + (b * kSteps + (s + 1)) * kI + k4 * 4);
        }
        waitvm();
        #pragma unroll
        for (int u2 = 0; u2 < 2; ++u2) {
          int idx = tid + u2 * 256; int b = idx >> 4, k4 = idx & 15;
          *(float4*)&sm[b * 68 + k4 * 4] = tm[u2];
          if (encx)
            *(float4*)&sx[b * 68 + k4 * 4] =
                *(const float4*)(x + (b * kT + s + 1) * kI + k4 * 4);
        }
        __syncthreads();
        const int b = tid >> 3, jj = tid & 7;
        const float4* sx4 = (const float4*)sx;
        const float4* sm4 = (const float4*)sm;
        const float4* w4p = (const float4*)we1;
        float a0 = 0, a1 = 0, a2 = 0, a3 = 0;
        if (encx) {
          for (int k4 = 0; k4 < 16; ++k4) {
            float4 xv = sx4[b * 17 + k4], w = w4p[jj * 33 + k4];
            a0 += xv.x * w.x; a1 += xv.y * w.y; a2 += xv.z * w.z; a3 += xv.w * w.w;
          }
        }
        for (int k4 = 0; k4 < 16; ++k4) {
          float4 mv = sm4[b * 17 + k4], w = w4p[jj * 33 + 16 + k4];
          a0 += mv.x * w.x; a1 += mv.y * w.y; a2 += mv.z * w.z; a3 += mv.w * w.w;
        }
        cstore(&linB[((s + 1) & 1) * 8192 + b * 256 + jb + jj],
               ((a0 + a1) + (a2 + a3)) + sb1[jj]);
        __syncthreads();
      }
    } else if (bid < 112) {
      // ===== F1 (decoder): tiled 4b x 4col, k-split 8 =====
      if (s >= kT + 1 && s <= kSteps) {
        float* wf1 = S; float* sHf = S + 4160; float* red = S + 12480; // [512][8]
        const float* hR = hBuf + (s & 1) * 8192;
        float4 th[8];
        #pragma unroll
        for (int u8 = 0; u8 < 8; ++u8) th[u8] = cload4(hR + (tid + u8 * 256) * 4);
        waitvm();
        #pragma unroll
        for (int u8 = 0; u8 < 8; ++u8) {
          int idx = tid + u8 * 256; int b = idx >> 6, k4 = idx & 63;
          *(float4*)&sHf[b * 260 + k4 * 4] = th[u8];
        }
        __syncthreads();
        const float4* sH4 = (const float4*)sHf;
        const float4* w4p = (const float4*)wf1;
        const int cq = tid & 3, b4 = (tid >> 2) & 7, kq = tid >> 5; // kq 0..7
        float acc[16];
        #pragma unroll
        for (int a = 0; a < 16; ++a) acc[a] = 0.f;
        for (int kk = 0; kk < 8; ++kk) {
          int k4 = kq * 8 + kk;
          float4 wr[4];
          #pragma unroll
          for (int ci = 0; ci < 4; ++ci) wr[ci] = w4p[(cq * 4 + ci) * 65 + k4];
          #pragma unroll
          for (int bi = 0; bi < 4; ++bi) {
            float4 h4 = sH4[(bi * 8 + b4) * 65 + k4];
            #pragma unroll
            for (int ci = 0; ci < 4; ++ci) {
              float4 w = wr[ci];
              acc[bi * 4 + ci] += h4.x * w.x + h4.y * w.y + h4.z * w.z + h4.w * w.w;
            }
          }
        }
        #pragma unroll
        for (int bi = 0; bi < 4; ++bi)
          #pragma unroll
          for (int ci = 0; ci < 4; ++ci) {
            int o = (bi * 8 + b4) * 16 + cq * 4 + ci;
            red[o * 8 + kq] = acc[bi * 4 + ci];
          }
        __syncthreads();
        #pragma unroll
        for (int u2 = 0; u2 < 2; ++u2) {
          int o = tid * 2 + u2; int b = o >> 4, col = o & 15;
          float4 v0 = *(const float4*)&red[o * 8];
          float4 v1 = *(const float4*)&red[o * 8 + 4];
          float v = ((v0.x + v0.y) + (v0.z + v0.w)) +
                    ((v1.x + v1.y) + (v1.z + v1.w)) + sb1[col];
          cstore(&o1B[(s & 1) * 8192 + b * 256 + (bid - 96) * 16 + col],
                 v > 0.f ? v : 0.f);
        }
        __syncthreads();
      }
    } else if (bid < 120) {
      // ===== F2 (decoder): tiled 4b x 1col, k-split 4 =====
      if (s >= kT + 2) {
        float* wf2 = S; float* sO = S + 2080; float* red = S + 10400; // [256][4]
        const float* oR = o1B + ((s - 1) & 1) * 8192;
        float4 to[8];
        #pragma unroll
        for (int u8 = 0; u8 < 8; ++u8) to[u8] = cload4(oR + (tid + u8 * 256) * 4);
        waitvm();
        #pragma unroll
        for (int u8 = 0; u8 < 8; ++u8) {
          int idx = tid + u8 * 256; int b = idx >> 6, k4 = idx & 63;
          *(float4*)&sO[b * 260 + k4 * 4] = to[u8];
        }
        __syncthreads();
        const float4* sO4 = (const float4*)sO;
        const float4* w4p = (const float4*)wf2;
        const int c = tid & 7, b4 = (tid >> 3) & 7, kq = tid >> 6; // kq 0..3
        float acc[4] = {0.f, 0.f, 0.f, 0.f};
        for (int kk = 0; kk < 16; ++kk) {
          int k4 = kq * 16 + kk;
          float4 w = w4p[c * 65 + k4];
          #pragma unroll
          for (int bi = 0; bi < 4; ++bi) {
            float4 o4 = sO4[(bi * 8 + b4) * 65 + k4];
            acc[bi] += o4.x * w.x + o4.y * w.y + o4.z * w.z + o4.w * w.w;
          }
        }
        #pragma unroll
        for (int bi = 0; bi < 4; ++bi) {
          int o = (bi * 8 + b4) * 8 + c;
          red[o * 4 + kq] = acc[bi];
        }
        __syncthreads();
        { int o = tid; int b = o >> 3, col = o & 7;
          float4 v = *(const float4*)&red[o * 4];
          out[(b * kOut + (s - 2 - kT)) * kC + (bid - 112) * 8 + col] =
              ((v.x + v.y) + (v.z + v.w)) + sb2[col];
        }
        __syncthreads();
      }
    } else {
      // ===== DG: dg1 tiled c8 x b4, k-split 8, + dg2/argmax/scatter/corr ===
      if (s < kT) {
        float* wdg1 = S; float* wdg2 = S + 10368;
        float* sXH = S + 11392;                     // [32][324]
        float* red = S + 21760;                     // [1024][8]
        float* l1s = S + 29952;                     // [32][36]
        const float* hR = hBuf + (s & 1) * 8192;
        float4 th[8];
        #pragma unroll
        for (int u8 = 0; u8 < 8; ++u8) th[u8] = cload4(hR + (tid + u8 * 256) * 4);
        waitvm();
        #pragma unroll
        for (int u8 = 0; u8 < 8; ++u8) {
          int idx = tid + u8 * 256; int b = idx >> 6, k4 = idx & 63;
          *(float4*)&sXH[b * 324 + 64 + k4 * 4] = th[u8];
        }
        #pragma unroll
        for (int u2 = 0; u2 < 2; ++u2) {
          int idx = tid + u2 * 256; int b = idx >> 4, k4 = idx & 15;
          *(float4*)&sXH[b * 324 + k4 * 4] =
              *(const float4*)(x + (b * kT + s) * kI + k4 * 4);
        }
        __syncthreads();
        { // l1 pre-act: tile (8 cols x 4 batches), k-split 8 over K4=80
          const float4* sA4 = (const float4*)sXH;   // stride 81 float4
          const float4* wd4 = (const float4*)wdg1;  // stride 81 float4
          const int cgrp = tid & 3, bgrp = (tid >> 2) & 7, kq = tid >> 5;
          float acc[32];
          #pragma unroll
          for (int a = 0; a < 32; ++a) acc[a] = 0.f;
          for (int kk = 0; kk < 10; ++kk) {
            int k4 = kq * 10 + kk;
            float4 wr[8];
            #pragma unroll
            for (int ci = 0; ci < 8; ++ci) wr[ci] = wd4[(cgrp * 8 + ci) * 81 + k4];
            #pragma unroll
            for (int bi = 0; bi < 4; ++bi) {
              float4 a4 = sA4[(bgrp * 4 + bi) * 81 + k4];
              #pragma unroll
              for (int ci = 0; ci < 8; ++ci) {
                float4 w = wr[ci];
                acc[ci * 4 + bi] += a4.x * w.x + a4.y * w.y + a4.z * w.z + a4.w * w.w;
              }
            }
          }
          #pragma unroll
          for (int ci = 0; ci < 8; ++ci)
            #pragma unroll
            for (int bi = 0; bi < 4; ++bi) {
              int o = (bgrp * 4 + bi) * 32 + cgrp * 8 + ci;
              red[o * 8 + kq] = acc[ci * 4 + bi];
            }
          __syncthreads();
          #pragma unroll
          for (int u4 = 0; u4 < 4; ++u4) {
            int o = tid * 4 + u4; int b = o >> 5, col = o & 31;
            float4 v0 = *(const float4*)&red[o * 8];
            float4 v1 = *(const float4*)&red[o * 8 + 4];
            l1s[b * 36 + col] = elu1(((v0.x + v0.y) + (v0.z + v0.w)) +
                                     ((v1.x + v1.y) + (v1.z + v1.w)) + sb1[col]);
          }
        }
        __syncthreads();
        for (int it = 0; it < 4; ++it) {          // dg2 + gumbel
          int i = tid + it * 256; int b = i >> 5, j = i & 31;
          float sv = sb2[j];
          for (int k = 0; k < 32; ++k) sv += l1s[b * 36 + k] * wdg2[k * 32 + j];
          lgarr[b * 33 + j] = sv + g[(s * 32 + b) * 32 + j];
        }
        __syncthreads();
        if (tid < 32) {
          float best = lgarr[tid * 33]; int bi = 0;
          for (int j = 1; j < 32; ++j) {
            float v = lgarr[tid * 33 + j];
            if (v > best) { best = v; bi = j; }
          }
          sel[tid] = bi;
        }
        __syncthreads();
        for (int it = 0; it < 8; ++it) {          // mem events, d >= 1
          int i = tid + it * 256; int b = i >> 6, ii = i & 63;
          int d = sel[b];
          if (d > 0) {
            int c = s + 1 + d, e = -1;
            if (c < kT) e = c;
            else { int rr = c - kT - 1;
                   if (rr >= 0 && !(rr & 1)) { int kk = rr >> 1; if (kk < kOut) e = kT + kk; } }
            if (e >= 0) {
              float* p = &mem[(b * kSteps + e) * kI + ii];
              cstore(p, cload(p) + sXH[b * 324 + ii] * dec_sh[d]);
            }
          }
        }
        { // corr (d == 0 event, lands in lin_{s+1} e1-space), parity (s+1)&1
          int j = tid;
          const int p1 = (s + 1) & 1;
          for (int b = 0; b < 32; ++b) {
            float val = 0.f;
            if (sel[b] == 0 && s < kT - 1) {
              float a = 0.f;
              #pragma unroll 8
              for (int k = 0; k < 64; ++k)
                a += sXH[b * 324 + k] * W_e1[(64 + k) * 256 + j];
              val = 0.99f * a;
            }
            cstore(&corrB[p1 * 8192 + b * 256 + j], val);
          }
        }
      }
    }
    gridbar_nf(baru, nr, grp, gsz); nr++;
  }
}

extern "C" void kernel_launch(void* const* d_in, const int* in_sizes, int n_in,
                              void* d_out, int out_size, void* d_ws, size_t ws_size,
                              hipStream_t stream) {
  (void)in_sizes; (void)n_in; (void)out_size; (void)ws_size;
  const float* x      = (const float*)d_in[0];
  const int*   lens   = (const int*)  d_in[1];
  const float* W_dg1  = (const float*)d_in[3];
  const float* b_dg1  = (const float*)d_in[4];
  const float* W_dg2  = (const float*)d_in[5];
  const float* b_dg2  = (const float*)d_in[6];
  const float* W_e1   = (const float*)d_in[7];
  const float* b_e1   = (const float*)d_in[8];
  const float* W_e2   = (const float*)d_in[9];
  const float* b_e2   = (const float*)d_in[10];
  const float* W_ih   = (const float*)d_in[11];
  const float* b_ih   = (const float*)d_in[12];
  const float* W_hh   = (const float*)d_in[13];
  const float* b_hh   = (const float*)d_in[14];
  const float* W_f1   = (const float*)d_in[15];
  const float* b_f1   = (const float*)d_in[16];
  const float* W_f2   = (const float*)d_in[17];
  const float* b_f2   = (const float*)d_in[18];

  hipMemsetAsync(d_ws, 0, WS_ZERO_BYTES, stream);
  delay_rnn<<<dim3(NB), dim3(NTHR), 0, stream>>>(
      x, lens, W_dg1, b_dg1, W_dg2, b_dg2, W_e1, b_e1, W_e2, b_e2,
      W_ih, b_ih, W_hh, b_hh, W_f1, b_f1, W_f2, b_f2,
      (float*)d_out, (float*)d_ws);
}

// Round 10
// 2518.236 us; speedup vs baseline: 1.1581x; 1.1581x over previous
//
#include <hip/hip_runtime.h>
#include <math.h>

// ---------------------------------------------------------------------------
// DelayRNN persistent kernel, R10 = R8 structure (89 blocks, proven 2735us)
//  + conflict-free LDS reduce layouts (R8/R9 red[] had 16..32-way write
//    conflicts: bank depended only on c/cq; now bank is linear in lane)
//  + corr GEMM eliminated: P[s][b][j] = x_s @ W_e1[64:128] precomputed in
//    init; DG publishes sel[] (sc1); GRU derives corr inline from plain-L2
//    P reads. DG's per-thread 2048-FMA + 2048-global-load corr loop deleted.
// Roles: 32 GRU | 32 E1 | 16 F1 | 8 F2 | 1 DG. One tree barrier per step.
// ---------------------------------------------------------------------------

#define kB 32
#define kT 128
#define kI 64
#define kH 256
#define kD 32
#define kC 64
#define kOut 32
#define kSteps (kT + kOut)            // 160
#define NB 89
#define NTHR 256
#define NT_ALL (NB * NTHR)
#define BPG 12
#define NGRP 8

// ws float offsets. Zeroed region: [0, WS_NZ)
#define WS_H     384                   // h[2][32][256]
#define WS_SEL   (WS_H + 2*8192)       // sel[2][32] (int)
#define WS_MEM   (WS_SEL + 64)         // mem events [32][160][64]
#define WS_NZ    (WS_MEM + kB*kSteps*kI)
#define WS_LIN   WS_NZ                 // lin[2][32][256] (pre-elu e1 out)
#define WS_O1    (WS_LIN + 2*8192)     // o1[2][32][256]
#define WS_W2    (WS_O1 + 2*8192)      // W2 = W_e2@W_ih [256][768]
#define WS_B2    (WS_W2 + kH*3*kH)     // B2 [768]
#define WS_G     (WS_B2 + 3*kH)        // gumbel [T*B*D]
#define WS_P     (WS_G + kT*kB*kD)     // P[s][b][j] = x_s @ W_e1[64:128]
#define WS_ZERO_BYTES ((size_t)WS_NZ * sizeof(float))

// ---- coherent scalar access (agent scope, L3 coherence point) ----
__device__ __forceinline__ float cload(const float* p) {
  return __hip_atomic_load(p, __ATOMIC_RELAXED, __HIP_MEMORY_SCOPE_AGENT);
}
__device__ __forceinline__ void cstore(float* p, float v) {
  __hip_atomic_store(p, v, __ATOMIC_RELAXED, __HIP_MEMORY_SCOPE_AGENT);
}
__device__ __forceinline__ int cload_i(const int* p) {
  return __hip_atomic_load(p, __ATOMIC_RELAXED, __HIP_MEMORY_SCOPE_AGENT);
}
__device__ __forceinline__ void cstore_i(int* p, int v) {
  __hip_atomic_store(p, v, __ATOMIC_RELAXED, __HIP_MEMORY_SCOPE_AGENT);
}
__device__ __forceinline__ float4 cload4(const float* p) {
  float4 r;
  asm volatile("global_load_dwordx4 %0, %1, off sc0 sc1" : "=v"(r) : "v"(p));
  return r;
}
__device__ __forceinline__ void waitvm() {
  asm volatile("s_waitcnt vmcnt(0)" ::: "memory");
}

// ---- Threefry-2x32 (jax partitionable path) ----
__device__ __forceinline__ void tf2x32(unsigned k0, unsigned k1,
                                       unsigned x0, unsigned x1,
                                       unsigned& o0, unsigned& o1) {
  unsigned ks2 = k0 ^ k1 ^ 0x1BD11BDAu;
  unsigned v0 = x0 + k0, v1 = x1 + k1;
#define TFR(r) { v0 += v1; v1 = (v1 << (r)) | (v1 >> (32-(r))); v1 ^= v0; }
  TFR(13) TFR(15) TFR(26) TFR(6)   v0 += k1;  v1 += ks2 + 1u;
  TFR(17) TFR(29) TFR(16) TFR(24)  v0 += ks2; v1 += k0  + 2u;
  TFR(13) TFR(15) TFR(26) TFR(6)   v0 += k0;  v1 += k1  + 3u;
  TFR(17) TFR(29) TFR(16) TFR(24)  v0 += k1;  v1 += ks2 + 4u;
  TFR(13) TFR(15) TFR(26) TFR(6)   v0 += ks2; v1 += k0  + 5u;
#undef TFR
  o0 = v0; o1 = v1;
}
__device__ __forceinline__ float bits_to_gumbel(unsigned bits) {
  float f = __uint_as_float((bits >> 9) | 0x3F800000u) - 1.0f;
  float u = f + 1.17549435e-38f;
  return -logf(-logf(u));
}

__device__ __forceinline__ void gridbar_full(unsigned* u, unsigned target) {
  __syncthreads();
  if (threadIdx.x == 0) {
    __threadfence();
    __hip_atomic_fetch_add(&u[320], 1u, __ATOMIC_ACQ_REL, __HIP_MEMORY_SCOPE_AGENT);
    while (__hip_atomic_load(&u[320], __ATOMIC_RELAXED, __HIP_MEMORY_SCOPE_AGENT) < target)
      __builtin_amdgcn_s_sleep(1);
    __threadfence();
  }
  __syncthreads();
}
__device__ __forceinline__ void gridbar_nf(unsigned* u, unsigned nround,
                                           int grp, int gsz) {
  asm volatile("s_waitcnt vmcnt(0) lgkmcnt(0)" ::: "memory");
  __syncthreads();
  if (threadIdx.x == 0) {
    unsigned old = __hip_atomic_fetch_add(&u[grp * 32], 1u,
                      __ATOMIC_RELAXED, __HIP_MEMORY_SCOPE_AGENT);
    if (old + 1u == (unsigned)gsz * nround) {
      unsigned r = __hip_atomic_fetch_add(&u[256], 1u,
                      __ATOMIC_RELAXED, __HIP_MEMORY_SCOPE_AGENT);
      if (r + 1u == NGRP * nround)
        __hip_atomic_store(&u[288], nround, __ATOMIC_RELAXED, __HIP_MEMORY_SCOPE_AGENT);
    }
    while (__hip_atomic_load(&u[288], __ATOMIC_RELAXED, __HIP_MEMORY_SCOPE_AGENT) < nround)
      __builtin_amdgcn_s_sleep(2);
    asm volatile("" ::: "memory");
  }
  __syncthreads();
}

__device__ __forceinline__ float elu1(float v) { return v > 0.f ? v : expm1f(v); }

__global__ __launch_bounds__(NTHR)
void delay_rnn(const float* __restrict__ x, const int* __restrict__ lengths,
               const float* __restrict__ W_dg1, const float* __restrict__ b_dg1,
               const float* __restrict__ W_dg2, const float* __restrict__ b_dg2,
               const float* __restrict__ W_e1,  const float* __restrict__ b_e1,
               const float* __restrict__ W_e2,  const float* __restrict__ b_e2,
               const float* __restrict__ W_ih,  const float* __restrict__ b_ih,
               const float* __restrict__ W_hh,  const float* __restrict__ b_hh,
               const float* __restrict__ W_f1,  const float* __restrict__ b_f1,
               const float* __restrict__ W_f2,  const float* __restrict__ b_f2,
               float* __restrict__ out, float* __restrict__ ws) {
  const int tid = threadIdx.x;
  const int bid = blockIdx.x;
  const int gid = bid * NTHR + tid;
  const int grp = bid / BPG;
  const int gsz = (grp == NGRP - 1) ? (NB - (NGRP - 1) * BPG) : BPG;

  unsigned* baru = (unsigned*)ws;
  float* hBuf  = ws + WS_H;
  int*   selG  = (int*)(ws + WS_SEL);
  float* mem   = ws + WS_MEM;
  float* linB  = ws + WS_LIN;
  float* o1B   = ws + WS_O1;
  float* W2g   = ws + WS_W2;
  float* B2g   = ws + WS_B2;
  float* g     = ws + WS_G;
  float* Pg    = ws + WS_P;

  __shared__ float S[35264];           // role-carved (max: GRU)
  __shared__ float lgarr[1056];
  __shared__ float sb1[32], sb2[32], dec_sh[32];
  __shared__ int   sel[32], len_s[32];

  // ---------------- init: gumbel, W2 = W_e2@W_ih, B2, P ----------------
  {
    unsigned k0, k1;
    tf2x32(0u, 42u, 0u, 0u, k0, k1);
    for (int i = gid; i < kT * kB * kD; i += NT_ALL) {
      unsigned a, b;
      tf2x32(k0, k1, 0u, (unsigned)i, a, b);
      g[i] = bits_to_gumbel(a ^ b);
    }
  }
  for (int idx = gid; idx < kH * 3 * kH; idx += NT_ALL) {
    int k = idx / (3 * kH), n = idx % (3 * kH);
    const float* wr = W_e2 + k * kH;
    float s0 = 0, s1 = 0, s2 = 0, s3 = 0;
    for (int m = 0; m < kH; m += 4) {
      float4 wv = *(const float4*)(wr + m);
      s0 += wv.x * W_ih[(m    ) * 3 * kH + n];
      s1 += wv.y * W_ih[(m + 1) * 3 * kH + n];
      s2 += wv.z * W_ih[(m + 2) * 3 * kH + n];
      s3 += wv.w * W_ih[(m + 3) * 3 * kH + n];
    }
    W2g[idx] = ((s0 + s1) + (s2 + s3));
  }
  for (int n = gid; n < 3 * kH; n += NT_ALL) {
    float s = b_ih[n];
    for (int m = 0; m < kH; ++m) s += b_e2[m] * W_ih[m * 3 * kH + n];
    B2g[n] = s;
  }
  // P[s][b][j] = sum_k x[b,s,k] * W_e1[64+k][j]
  for (int idx = gid; idx < kT * kB * kH; idx += NT_ALL) {
    int s = idx >> 13, r = idx & 8191, b = r >> 8, j = r & 255;
    const float* xr = x + (b * kT + s) * kI;
    float a0 = 0, a1 = 0, a2 = 0, a3 = 0;
    for (int k = 0; k < 64; k += 4) {
      float4 xv = *(const float4*)(xr + k);
      a0 += xv.x * W_e1[(64 + k) * 256 + j];
      a1 += xv.y * W_e1[(65 + k) * 256 + j];
      a2 += xv.z * W_e1[(66 + k) * 256 + j];
      a3 += xv.w * W_e1[(67 + k) * 256 + j];
    }
    Pg[idx] = ((a0 + a1) + (a2 + a3));
  }

  gridbar_full(baru, NB);

  // ---------------- persistent LDS weight staging ----------------
  if (bid < 32) {                                   // GRU: W_hh + W2 slices
    float* whh = S; float* w2 = S + 6240;
    const int jb = bid * 8;
    for (int i = tid; i < 6144; i += NTHR) {
      int gg = i >> 11, r = i & 2047, jj = r >> 8, k = r & 255;
      whh[(gg * 8 + jj) * 260 + k] = W_hh[k * 768 + gg * 256 + jb + jj];
      w2 [(gg * 8 + jj) * 260 + k] = W2g [k * 768 + gg * 256 + jb + jj];
    }
    if (tid < 24) { int gg = tid / 8, jj = tid % 8;
      sb1[tid] = b_hh[gg * 256 + jb + jj];
      sb2[tid] = B2g [gg * 256 + jb + jj];
    }
    if (tid < 32) len_s[tid] = lengths[tid];
  } else if (bid < 64) {                            // E1 + lin_0
    float* we1 = S;
    const int jb = (bid - 32) * 8;
    for (int i = tid; i < 1024; i += NTHR) {
      int jj = i >> 7, k = i & 127;
      we1[jj * 132 + k] = W_e1[k * 256 + jb + jj];
    }
    if (tid < 8) sb1[tid] = b_e1[jb + tid];
    __syncthreads();
    { int b = tid >> 3, jj = tid & 7;               // lin_0 = x_0@We1[:64]+b
      const float* xr = x + (b * kT) * kI;
      float a0 = 0, a1 = 0, a2 = 0, a3 = 0;
      for (int k = 0; k < 64; k += 4) {
        float4 xv = *(const float4*)(xr + k);
        a0 += xv.x * we1[jj * 132 + k];
        a1 += xv.y * we1[jj * 132 + k + 1];
        a2 += xv.z * we1[jj * 132 + k + 2];
        a3 += xv.w * we1[jj * 132 + k + 3];
      }
      cstore(&linB[b * 256 + jb + jj], ((a0 + a1) + (a2 + a3)) + sb1[jj]);
    }
  } else if (bid < 80) {                            // F1
    float* wf1 = S;
    const int jb = (bid - 64) * 16;
    for (int i = tid; i < 4096; i += NTHR) {
      int jj = i >> 8, k = i & 255;
      wf1[jj * 260 + k] = W_f1[k * 256 + jb + jj];
    }
    if (tid < 16) sb1[tid] = b_f1[jb + tid];
  } else if (bid < 88) {                            // F2
    float* wf2 = S;
    const int cb = (bid - 80) * 8;
    for (int i = tid; i < 2048; i += NTHR) {
      int cc = i >> 8, k = i & 255;
      wf2[cc * 260 + k] = W_f2[k * 64 + cb + cc];
    }
    if (tid < 8) sb2[tid] = b_f2[cb + tid];
  } else {                                          // DG
    float* wdg1 = S; float* wdg2 = S + 10368;
    for (int i = tid; i < 10240; i += NTHR) {
      int j = i / 320, k = i % 320;
      wdg1[j * 324 + k] = W_dg1[k * 32 + j];
    }
    for (int i = tid; i < 1024; i += NTHR) wdg2[i] = W_dg2[i];
    if (tid < 32) { sb1[tid] = b_dg1[tid]; sb2[tid] = b_dg2[tid];
                    dec_sh[tid] = powf(0.99f, (float)(tid + 1)); }
  }

  unsigned nr = 1;
  gridbar_nf(baru, nr, grp, gsz); nr++;

  // ---------------- time loop: ONE barrier per phase ----------------
  for (int s = 0; s <= kSteps + 1; ++s) {
    if (bid < 32) {
      // ===== GRU (+inline gh) for step s, tiled 4b x 1col x 6rows =====
      if (s < kSteps) {
        float* whh = S; float* w2 = S + 6240;
        float* sH = S + 12480; float* sLin = S + 20800;
        float* red = S + 29120;                     // [4][1536], bank=lane
        const float* hR = hBuf + (s & 1) * 8192;
        const float* lR = linB + (s & 1) * 8192;
        const bool useC = (s >= 1 && s < kT);       // corr from enc step s-1
        const float4* P4 = (const float4*)(Pg + (s - 1) * 8192);
        const int* selR = selG + ((s - 1) & 1) * 32;
        float4 th[8], tl[8], tp[8];
        int tsel[8];
        #pragma unroll
        for (int u8 = 0; u8 < 8; ++u8) {
          int i4 = (tid + u8 * 256) * 4;
          th[u8] = cload4(hR + i4);
          tl[u8] = cload4(lR + i4);
        }
        if (useC) {
          #pragma unroll
          for (int u8 = 0; u8 < 8; ++u8) {
            int idx = tid + u8 * 256; int b = idx >> 6, k4 = idx & 63;
            tp[u8] = P4[b * 64 + k4];               // plain (L2-cached, immutable)
            tsel[u8] = cload_i(&selR[b]);
          }
        }
        waitvm();
        #pragma unroll
        for (int u8 = 0; u8 < 8; ++u8) {
          int idx = tid + u8 * 256; int b = idx >> 6, k4 = idx & 63;
          *(float4*)&sH[b * 260 + k4 * 4] = th[u8];
          float cx = 0.f, cy = 0.f, cz = 0.f, cw = 0.f;
          if (useC && tsel[u8] == 0) {
            cx = 0.99f * tp[u8].x; cy = 0.99f * tp[u8].y;
            cz = 0.99f * tp[u8].z; cw = 0.99f * tp[u8].w;
          }
          float4 v;
          v.x = elu1(tl[u8].x + cx);
          v.y = elu1(tl[u8].y + cy);
          v.z = elu1(tl[u8].z + cz);
          v.w = elu1(tl[u8].w + cw);
          *(float4*)&sLin[b * 260 + k4 * 4] = v;
        }
        __syncthreads();
        const float4* sH4 = (const float4*)sH;
        const float4* sL4 = (const float4*)sLin;
        const float4* wh4 = (const float4*)whh;
        const float4* w24 = (const float4*)w2;
        const int c  = tid & 7;
        const int b4 = (tid >> 3) & 7;
        const int kq = tid >> 6;                    // 0..3, k-chunk 64
        float acc[24];
        #pragma unroll
        for (int a = 0; a < 24; ++a) acc[a] = 0.f;
        for (int kk = 0; kk < 16; ++kk) {
          int k4 = kq * 16 + kk;
          float4 wr[6];
          #pragma unroll
          for (int gg = 0; gg < 3; ++gg) {
            wr[gg]     = wh4[(gg * 8 + c) * 65 + k4];
            wr[3 + gg] = w24[(gg * 8 + c) * 65 + k4];
          }
          #pragma unroll
          for (int bi = 0; bi < 4; ++bi) {
            int b = bi * 8 + b4;
            float4 h4 = sH4[b * 65 + k4];
            float4 l4 = sL4[b * 65 + k4];
            #pragma unroll
            for (int gg = 0; gg < 3; ++gg) {
              float4 w = wr[gg];
              acc[bi * 6 + gg]     += h4.x * w.x + h4.y * w.y + h4.z * w.z + h4.w * w.w;
              w = wr[3 + gg];
              acc[bi * 6 + 3 + gg] += l4.x * w.x + l4.y * w.y + l4.z * w.z + l4.w * w.w;
            }
          }
        }
        // red[kq][rr][b*8+c]: write addr = const + lane -> conflict-free
        #pragma unroll
        for (int bi = 0; bi < 4; ++bi)
          #pragma unroll
          for (int rr = 0; rr < 6; ++rr)
            red[kq * 1536 + rr * 256 + (bi * 8 + b4) * 8 + c] = acc[bi * 6 + rr];
        __syncthreads();
        { // epilogue: thread -> (b, col)
          int b = tid >> 3, cc = tid & 7, jg = bid * 8 + cc;
          int lo = b * 8 + cc;
          float dots[6];
          #pragma unroll
          for (int rr = 0; rr < 6; ++rr)
            dots[rr] = (red[rr * 256 + lo] + red[1536 + rr * 256 + lo]) +
                       (red[3072 + rr * 256 + lo] + red[4608 + rr * 256 + lo]);
          float ghr = dots[0] + sb1[cc];
          float ghz = dots[1] + sb1[8 + cc];
          float ghn = dots[2] + sb1[16 + cc];
          float gir = dots[3] + sb2[cc];
          float giz = dots[4] + sb2[8 + cc];
          float gin = dots[5] + sb2[16 + cc];
          float r = 1.f / (1.f + expf(-(gir + ghr)));
          float z = 1.f / (1.f + expf(-(giz + ghz)));
          float n = tanhf(gin + r * ghn);
          float hold = sH[b * 260 + jg];
          float nh = (1.f - z) * n + z * hold;
          float hv = (s < kT) ? ((s < len_s[b]) ? nh : hold) : nh;
          cstore(&hBuf[((s + 1) & 1) * 8192 + b * 256 + jg], hv);
        }
      }
    } else if (bid < 64) {
      // ===== E1: lin_{s+1} (pre-elu) =====
      if (s <= kSteps - 2) {
        float* we1 = S; float* sx = S + 1056; float* sm = S + 3232;
        const int jb = (bid - 32) * 8;
        const bool encx = (s + 1 < kT);
        float4 tm[2];
        #pragma unroll
        for (int u2 = 0; u2 < 2; ++u2) {
          int idx = tid + u2 * 256; int b = idx >> 4, k4 = idx & 15;
          tm[u2] = cload4(mem + (b * kSteps + (s + 1)) * kI + k4 * 4);
        }
        waitvm();
        #pragma unroll
        for (int u2 = 0; u2 < 2; ++u2) {
          int idx = tid + u2 * 256; int b = idx >> 4, k4 = idx & 15;
          *(float4*)&sm[b * 68 + k4 * 4] = tm[u2];
          if (encx)
            *(float4*)&sx[b * 68 + k4 * 4] =
                *(const float4*)(x + (b * kT + s + 1) * kI + k4 * 4);
        }
        __syncthreads();
        const int b = tid >> 3, jj = tid & 7;
        const float4* sx4 = (const float4*)sx;
        const float4* sm4 = (const float4*)sm;
        const float4* w4p = (const float4*)we1;
        float a0 = 0, a1 = 0, a2 = 0, a3 = 0;
        if (encx) {
          for (int k4 = 0; k4 < 16; ++k4) {
            float4 xv = sx4[b * 17 + k4], w = w4p[jj * 33 + k4];
            a0 += xv.x * w.x; a1 += xv.y * w.y; a2 += xv.z * w.z; a3 += xv.w * w.w;
          }
        }
        for (int k4 = 0; k4 < 16; ++k4) {
          float4 mv = sm4[b * 17 + k4], w = w4p[jj * 33 + 16 + k4];
          a0 += mv.x * w.x; a1 += mv.y * w.y; a2 += mv.z * w.z; a3 += mv.w * w.w;
        }
        cstore(&linB[((s + 1) & 1) * 8192 + b * 256 + jb + jj],
               ((a0 + a1) + (a2 + a3)) + sb1[jj]);
        __syncthreads();
      }
    } else if (bid < 80) {
      // ===== F1 (decoder): tiled 4b x 4col, k-split 8 =====
      if (s >= kT + 1 && s <= kSteps) {
        float* wf1 = S; float* sHf = S + 4160; float* red = S + 12480; // [8][512]
        const float* hR = hBuf + (s & 1) * 8192;
        float4 th[8];
        #pragma unroll
        for (int u8 = 0; u8 < 8; ++u8) th[u8] = cload4(hR + (tid + u8 * 256) * 4);
        waitvm();
        #pragma unroll
        for (int u8 = 0; u8 < 8; ++u8) {
          int idx = tid + u8 * 256; int b = idx >> 6, k4 = idx & 63;
          *(float4*)&sHf[b * 260 + k4 * 4] = th[u8];
        }
        __syncthreads();
        const float4* sH4 = (const float4*)sHf;
        const float4* w4p = (const float4*)wf1;
        const int cq = tid & 3, b4 = (tid >> 2) & 7, kq = tid >> 5; // kq 0..7
        float acc[16];
        #pragma unroll
        for (int a = 0; a < 16; ++a) acc[a] = 0.f;
        for (int kk = 0; kk < 8; ++kk) {
          int k4 = kq * 8 + kk;
          float4 wr[4];
          #pragma unroll
          for (int ci = 0; ci < 4; ++ci) wr[ci] = w4p[(cq * 4 + ci) * 65 + k4];
          #pragma unroll
          for (int bi = 0; bi < 4; ++bi) {
            float4 h4 = sH4[(bi * 8 + b4) * 65 + k4];
            #pragma unroll
            for (int ci = 0; ci < 4; ++ci) {
              float4 w = wr[ci];
              acc[bi * 4 + ci] += h4.x * w.x + h4.y * w.y + h4.z * w.z + h4.w * w.w;
            }
          }
        }
        // g = (bi*4+ci)*32 + cq*8 + b4 -> bank = (cq*8+b4)%32, conflict-free
        #pragma unroll
        for (int bi = 0; bi < 4; ++bi)
          #pragma unroll
          for (int ci = 0; ci < 4; ++ci)
            red[kq * 512 + (bi * 4 + ci) * 32 + cq * 8 + b4] = acc[bi * 4 + ci];
        __syncthreads();
        #pragma unroll
        for (int u2 = 0; u2 < 2; ++u2) {
          int o = tid * 2 + u2; int b = o >> 4, col = o & 15;
          int gg = ((b >> 3) * 4 + (col & 3)) * 32 + (col >> 2) * 8 + (b & 7);
          float v = 0.f;
          #pragma unroll
          for (int kq2 = 0; kq2 < 8; ++kq2) v += red[kq2 * 512 + gg];
          v += sb1[col];
          cstore(&o1B[(s & 1) * 8192 + b * 256 + (bid - 64) * 16 + col],
                 v > 0.f ? v : 0.f);
        }
        __syncthreads();
      }
    } else if (bid < 88) {
      // ===== F2 (decoder): tiled 4b x 1col, k-split 4 =====
      if (s >= kT + 2) {
        float* wf2 = S; float* sO = S + 2080; float* red = S + 10400; // [4][256]
        const float* oR = o1B + ((s - 1) & 1) * 8192;
        float4 to[8];
        #pragma unroll
        for (int u8 = 0; u8 < 8; ++u8) to[u8] = cload4(oR + (tid + u8 * 256) * 4);
        waitvm();
        #pragma unroll
        for (int u8 = 0; u8 < 8; ++u8) {
          int idx = tid + u8 * 256; int b = idx >> 6, k4 = idx & 63;
          *(float4*)&sO[b * 260 + k4 * 4] = to[u8];
        }
        __syncthreads();
        const float4* sO4 = (const float4*)sO;
        const float4* w4p = (const float4*)wf2;
        const int c = tid & 7, b4 = (tid >> 3) & 7, kq = tid >> 6; // kq 0..3
        float acc[4] = {0.f, 0.f, 0.f, 0.f};
        for (int kk = 0; kk < 16; ++kk) {
          int k4 = kq * 16 + kk;
          float4 w = w4p[c * 65 + k4];
          #pragma unroll
          for (int bi = 0; bi < 4; ++bi) {
            float4 o4 = sO4[(bi * 8 + b4) * 65 + k4];
            acc[bi] += o4.x * w.x + o4.y * w.y + o4.z * w.z + o4.w * w.w;
          }
        }
        // red[kq][bi*64 + b4*8 + c]: addr = const + lane -> conflict-free
        #pragma unroll
        for (int bi = 0; bi < 4; ++bi)
          red[kq * 256 + bi * 64 + b4 * 8 + c] = acc[bi];
        __syncthreads();
        { int b = tid >> 3, col = tid & 7;
          int gg = (b >> 3) * 64 + (b & 7) * 8 + col;
          float v = (red[gg] + red[256 + gg]) + (red[512 + gg] + red[768 + gg]);
          out[(b * kOut + (s - 2 - kT)) * kC + (bid - 80) * 8 + col] =
              v + sb2[col];
        }
        __syncthreads();
      }
    } else {
      // ===== DG: dg1 tiled 4b x 4col k-split 4, dg2/argmax/scatter/sel =====
      if (s < kT) {
        float* wdg1 = S; float* wdg2 = S + 10368;
        float* sXH = S + 11392;                     // [32][324]
        float* red = S + 21760;                     // [4][1024]
        float* l1s = S + 25856;                     // [32][36]
        const float* hR = hBuf + (s & 1) * 8192;
        float4 th[8];
        #pragma unroll
        for (int u8 = 0; u8 < 8; ++u8) th[u8] = cload4(hR + (tid + u8 * 256) * 4);
        waitvm();
        #pragma unroll
        for (int u8 = 0; u8 < 8; ++u8) {
          int idx = tid + u8 * 256; int b = idx >> 6, k4 = idx & 63;
          *(float4*)&sXH[b * 324 + 64 + k4 * 4] = th[u8];
        }
        #pragma unroll
        for (int u2 = 0; u2 < 2; ++u2) {
          int idx = tid + u2 * 256; int b = idx >> 4, k4 = idx & 15;
          *(float4*)&sXH[b * 324 + k4 * 4] =
              *(const float4*)(x + (b * kT + s) * kI + k4 * 4);
        }
        __syncthreads();
        { // l1 pre-act: tile (4 batches x 4 cols), k-split 4 over K4=80
          const float4* sA4 = (const float4*)sXH;   // stride 81 float4
          const float4* wd4 = (const float4*)wdg1;  // stride 81 float4
          const int cq = tid & 7, b4 = (tid >> 3) & 7, kq = tid >> 6;
          float acc[16];
          #pragma unroll
          for (int a = 0; a < 16; ++a) acc[a] = 0.f;
          for (int kk = 0; kk < 20; ++kk) {
            int k4 = kq * 20 + kk;
            float4 wr[4];
            #pragma unroll
            for (int ci = 0; ci < 4; ++ci) wr[ci] = wd4[(cq * 4 + ci) * 81 + k4];
            #pragma unroll
            for (int bi = 0; bi < 4; ++bi) {
              float4 a4 = sA4[(bi * 8 + b4) * 81 + k4];
              #pragma unroll
              for (int ci = 0; ci < 4; ++ci) {
                float4 w = wr[ci];
                acc[bi * 4 + ci] += a4.x * w.x + a4.y * w.y + a4.z * w.z + a4.w * w.w;
              }
            }
          }
          // f = (ci*4+bi)*64 + cq*8 + b4 -> bank=(cq*8+b4)%32, 2-way max
          #pragma unroll
          for (int bi = 0; bi < 4; ++bi)
            #pragma unroll
            for (int ci = 0; ci < 4; ++ci)
              red[kq * 1024 + (ci * 4 + bi) * 64 + cq * 8 + b4] = acc[bi * 4 + ci];
          __syncthreads();
          #pragma unroll
          for (int u4 = 0; u4 < 4; ++u4) {
            int o = tid * 4 + u4; int b = o >> 5, col = o & 31;
            int ci = col & 3, cq2 = col >> 2, bi = b >> 3, b42 = b & 7;
            int f = (ci * 4 + bi) * 64 + cq2 * 8 + b42;
            float v = (red[f] + red[1024 + f]) + (red[2048 + f] + red[3072 + f]);
            l1s[b * 36 + col] = elu1(v + sb1[col]);
          }
        }
        __syncthreads();
        for (int it = 0; it < 4; ++it) {          // dg2 + gumbel
          int i = tid + it * 256; int b = i >> 5, j = i & 31;
          float sv = sb2[j];
          for (int k = 0; k < 32; ++k) sv += l1s[b * 36 + k] * wdg2[k * 32 + j];
          lgarr[b * 33 + j] = sv + g[(s * 32 + b) * 32 + j];
        }
        __syncthreads();
        if (tid < 32) {
          float best = lgarr[tid * 33]; int bi = 0;
          for (int j = 1; j < 32; ++j) {
            float v = lgarr[tid * 33 + j];
            if (v > best) { best = v; bi = j; }
          }
          sel[tid] = bi;
        }
        __syncthreads();
        if (tid < 32) cstore_i(&selG[(s & 1) * 32 + tid], sel[tid]);  // publish
        for (int it = 0; it < 8; ++it) {          // mem events, d >= 1
          int i = tid + it * 256; int b = i >> 6, ii = i & 63;
          int d = sel[b];
          if (d > 0) {
            int c = s + 1 + d, e = -1;
            if (c < kT) e = c;
            else { int rr = c - kT - 1;
                   if (rr >= 0 && !(rr & 1)) { int kk = rr >> 1; if (kk < kOut) e = kT + kk; } }
            if (e >= 0) {
              float* p = &mem[(b * kSteps + e) * kI + ii];
              cstore(p, cload(p) + sXH[b * 324 + ii] * dec_sh[d]);
            }
          }
        }
      }
    }
    gridbar_nf(baru, nr, grp, gsz); nr++;
  }
}

extern "C" void kernel_launch(void* const* d_in, const int* in_sizes, int n_in,
                              void* d_out, int out_size, void* d_ws, size_t ws_size,
                              hipStream_t stream) {
  (void)in_sizes; (void)n_in; (void)out_size; (void)ws_size;
  const float* x      = (const float*)d_in[0];
  const int*   lens   = (const int*)  d_in[1];
  const float* W_dg1  = (const float*)d_in[3];
  const float* b_dg1  = (const float*)d_in[4];
  const float* W_dg2  = (const float*)d_in[5];
  const float* b_dg2  = (const float*)d_in[6];
  const float* W_e1   = (const float*)d_in[7];
  const float* b_e1   = (const float*)d_in[8];
  const float* W_e2   = (const float*)d_in[9];
  const float* b_e2   = (const float*)d_in[10];
  const float* W_ih   = (const float*)d_in[11];
  const float* b_ih   = (const float*)d_in[12];
  const float* W_hh   = (const float*)d_in[13];
  const float* b_hh   = (const float*)d_in[14];
  const float* W_f1   = (const float*)d_in[15];
  const float* b_f1   = (const float*)d_in[16];
  const float* W_f2   = (const float*)d_in[17];
  const float* b_f2   = (const float*)d_in[18];

  hipMemsetAsync(d_ws, 0, WS_ZERO_BYTES, stream);
  delay_rnn<<<dim3(NB), dim3(NTHR), 0, stream>>>(
      x, lens, W_dg1, b_dg1, W_dg2, b_dg2, W_e1, b_e1, W_e2, b_e2,
      W_ih, b_ih, W_hh, b_hh, W_f1, b_f1, W_f2, b_f2,
      (float*)d_out, (float*)d_ws);
}

// Round 11
// 1936.220 us; speedup vs baseline: 1.5062x; 1.3006x over previous
//
#include <hip/hip_runtime.h>
#include <math.h>

// ---------------------------------------------------------------------------
// DelayRNN persistent kernel, R11: producer/consumer FLAG sync (no per-phase
// grid barrier). R10 post-mortem: 15.4us/phase vs ~5-6us computable work; the
// gap is tree-barrier RMW serialization + full-grid skew. R11: each role block
// loops independently; sync via per-block epoch flags (own 64B line; arrival =
// one parallel sc1 store, detection = per-thread poll + __syncthreads_count).
// Buffers parity-4 (h, lin, o1, sel); pacing thresholds cover WAR:
//   GRU_s : FL_H>=s, FL_E1>=s+1, FL_DG>=min(s,128) [s>=1], FL_F1>=s-2 [s>=132]
//   DG_s  : FL_H>=s                         (s in 0..127)
//   E1_e  : FL_DG>=clamp(e-1,0,128), FL_H>=e-2        (e in 0..159)
//   F1_s  : FL_H>=s, FL_F2>=s-2 [s>=133]    (s in 129..160)
//   F2_s  : FL_F1>=s                        (s in 130..161)
// Role bodies identical to R10 (tiles, conflict-free reduces, P-based corr).
// ---------------------------------------------------------------------------

#define kB 32
#define kT 128
#define kI 64
#define kH 256
#define kD 32
#define kC 64
#define kOut 32
#define kSteps (kT + kOut)            // 160
#define NB 89
#define NTHR 256
#define NT_ALL (NB * NTHR)

// ws float offsets. Zeroed region: [0, WS_NZ)
#define WS_FL    384                   // int flags FL[89] @ stride 16 ints
#define WS_H     1856                  // h[4][32][256]
#define WS_SEL   (WS_H + 4*8192)       // sel[4][32] (int)
#define WS_MEM   (WS_SEL + 128)        // mem events [32][160][64]
#define WS_NZ    (WS_MEM + kB*kSteps*kI)
#define WS_LIN   WS_NZ                 // lin[4][32][256] (pre-elu e1 out)
#define WS_O1    (WS_LIN + 4*8192)     // o1[4][32][256]
#define WS_W2    (WS_O1 + 4*8192)      // W2 = W_e2@W_ih [256][768]
#define WS_B2    (WS_W2 + kH*3*kH)     // B2 [768]
#define WS_G     (WS_B2 + 3*kH)        // gumbel [T*B*D]
#define WS_P     (WS_G + kT*kB*kD)     // P[s][b][j] = x_s @ W_e1[64:128]
#define WS_ZERO_BYTES ((size_t)WS_NZ * sizeof(float))

// ---- coherent scalar access (agent scope, L3 coherence point) ----
__device__ __forceinline__ float cload(const float* p) {
  return __hip_atomic_load(p, __ATOMIC_RELAXED, __HIP_MEMORY_SCOPE_AGENT);
}
__device__ __forceinline__ void cstore(float* p, float v) {
  __hip_atomic_store(p, v, __ATOMIC_RELAXED, __HIP_MEMORY_SCOPE_AGENT);
}
__device__ __forceinline__ int cload_i(const int* p) {
  return __hip_atomic_load(p, __ATOMIC_RELAXED, __HIP_MEMORY_SCOPE_AGENT);
}
__device__ __forceinline__ void cstore_i(int* p, int v) {
  __hip_atomic_store(p, v, __ATOMIC_RELAXED, __HIP_MEMORY_SCOPE_AGENT);
}
__device__ __forceinline__ float4 cload4(const float* p) {
  float4 r;
  asm volatile("global_load_dwordx4 %0, %1, off sc0 sc1" : "=v"(r) : "v"(p));
  return r;
}
__device__ __forceinline__ void waitvm() {
  asm volatile("s_waitcnt vmcnt(0)" ::: "memory");
}

// ---- flag sync ----
// FL[i]: i<32 GRU block i | i==32 DG | 33..64 E1 | 65..80 F1 | 81..88 F2.
// Each thread polls its assigned flag; thr<=0 means unconstrained.
__device__ __forceinline__ void poll(const int* FL, int tid,
                                     int tH, int tDG, int tE, int tF1, int tF2) {
  int thr;
  if      (tid < 32) thr = tH;
  else if (tid == 32) thr = tDG;
  else if (tid < 65) thr = tE;
  else if (tid < 81) thr = tF1;
  else if (tid < 89) thr = tF2;
  else thr = 0;
  const int* p = FL + tid * 16;
  for (;;) {
    int ok = (thr <= 0) || (cload_i(p) >= thr);
    if (__syncthreads_count(ok) == NTHR) return;
    __builtin_amdgcn_s_sleep(2);
  }
}
// Publish: all data stores drained per-wave, then block-sync, then flag store.
__device__ __forceinline__ void setflag(int* FL, int tid, int idx, int val) {
  waitvm();
  __syncthreads();
  if (tid == 0) cstore_i(FL + idx * 16, val);
}

// ---- Threefry-2x32 (jax partitionable path) ----
__device__ __forceinline__ void tf2x32(unsigned k0, unsigned k1,
                                       unsigned x0, unsigned x1,
                                       unsigned& o0, unsigned& o1) {
  unsigned ks2 = k0 ^ k1 ^ 0x1BD11BDAu;
  unsigned v0 = x0 + k0, v1 = x1 + k1;
#define TFR(r) { v0 += v1; v1 = (v1 << (r)) | (v1 >> (32-(r))); v1 ^= v0; }
  TFR(13) TFR(15) TFR(26) TFR(6)   v0 += k1;  v1 += ks2 + 1u;
  TFR(17) TFR(29) TFR(16) TFR(24)  v0 += ks2; v1 += k0  + 2u;
  TFR(13) TFR(15) TFR(26) TFR(6)   v0 += k0;  v1 += k1  + 3u;
  TFR(17) TFR(29) TFR(16) TFR(24)  v0 += k1;  v1 += ks2 + 4u;
  TFR(13) TFR(15) TFR(26) TFR(6)   v0 += ks2; v1 += k0  + 5u;
#undef TFR
  o0 = v0; o1 = v1;
}
__device__ __forceinline__ float bits_to_gumbel(unsigned bits) {
  float f = __uint_as_float((bits >> 9) | 0x3F800000u) - 1.0f;
  float u = f + 1.17549435e-38f;
  return -logf(-logf(u));
}

__device__ __forceinline__ void gridbar_full(unsigned* u, unsigned target) {
  __syncthreads();
  if (threadIdx.x == 0) {
    __threadfence();
    __hip_atomic_fetch_add(&u[320], 1u, __ATOMIC_ACQ_REL, __HIP_MEMORY_SCOPE_AGENT);
    while (__hip_atomic_load(&u[320], __ATOMIC_RELAXED, __HIP_MEMORY_SCOPE_AGENT) < target)
      __builtin_amdgcn_s_sleep(1);
    __threadfence();
  }
  __syncthreads();
}

__device__ __forceinline__ float elu1(float v) { return v > 0.f ? v : expm1f(v); }

__global__ __launch_bounds__(NTHR)
void delay_rnn(const float* __restrict__ x, const int* __restrict__ lengths,
               const float* __restrict__ W_dg1, const float* __restrict__ b_dg1,
               const float* __restrict__ W_dg2, const float* __restrict__ b_dg2,
               const float* __restrict__ W_e1,  const float* __restrict__ b_e1,
               const float* __restrict__ W_e2,  const float* __restrict__ b_e2,
               const float* __restrict__ W_ih,  const float* __restrict__ b_ih,
               const float* __restrict__ W_hh,  const float* __restrict__ b_hh,
               const float* __restrict__ W_f1,  const float* __restrict__ b_f1,
               const float* __restrict__ W_f2,  const float* __restrict__ b_f2,
               float* __restrict__ out, float* __restrict__ ws) {
  const int tid = threadIdx.x;
  const int bid = blockIdx.x;
  const int gid = bid * NTHR + tid;

  unsigned* baru = (unsigned*)ws;
  int*   FL    = (int*)(ws + WS_FL);
  float* hBuf  = ws + WS_H;
  int*   selG  = (int*)(ws + WS_SEL);
  float* mem   = ws + WS_MEM;
  float* linB  = ws + WS_LIN;
  float* o1B   = ws + WS_O1;
  float* W2g   = ws + WS_W2;
  float* B2g   = ws + WS_B2;
  float* g     = ws + WS_G;
  float* Pg    = ws + WS_P;

  __shared__ float S[35264];           // role-carved (max: GRU)
  __shared__ float lgarr[1056];
  __shared__ float sb1[32], sb2[32], dec_sh[32];
  __shared__ int   sel[32], len_s[32];

  // ---------------- init: gumbel, W2 = W_e2@W_ih, B2, P ----------------
  {
    unsigned k0, k1;
    tf2x32(0u, 42u, 0u, 0u, k0, k1);
    for (int i = gid; i < kT * kB * kD; i += NT_ALL) {
      unsigned a, b;
      tf2x32(k0, k1, 0u, (unsigned)i, a, b);
      g[i] = bits_to_gumbel(a ^ b);
    }
  }
  for (int idx = gid; idx < kH * 3 * kH; idx += NT_ALL) {
    int k = idx / (3 * kH), n = idx % (3 * kH);
    const float* wr = W_e2 + k * kH;
    float s0 = 0, s1 = 0, s2 = 0, s3 = 0;
    for (int m = 0; m < kH; m += 4) {
      float4 wv = *(const float4*)(wr + m);
      s0 += wv.x * W_ih[(m    ) * 3 * kH + n];
      s1 += wv.y * W_ih[(m + 1) * 3 * kH + n];
      s2 += wv.z * W_ih[(m + 2) * 3 * kH + n];
      s3 += wv.w * W_ih[(m + 3) * 3 * kH + n];
    }
    W2g[idx] = ((s0 + s1) + (s2 + s3));
  }
  for (int n = gid; n < 3 * kH; n += NT_ALL) {
    float s = b_ih[n];
    for (int m = 0; m < kH; ++m) s += b_e2[m] * W_ih[m * 3 * kH + n];
    B2g[n] = s;
  }
  // P[s][b][j] = sum_k x[b,s,k] * W_e1[64+k][j]
  for (int idx = gid; idx < kT * kB * kH; idx += NT_ALL) {
    int s = idx >> 13, r = idx & 8191, b = r >> 8, j = r & 255;
    const float* xr = x + (b * kT + s) * kI;
    float a0 = 0, a1 = 0, a2 = 0, a3 = 0;
    for (int k = 0; k < 64; k += 4) {
      float4 xv = *(const float4*)(xr + k);
      a0 += xv.x * W_e1[(64 + k) * 256 + j];
      a1 += xv.y * W_e1[(65 + k) * 256 + j];
      a2 += xv.z * W_e1[(66 + k) * 256 + j];
      a3 += xv.w * W_e1[(67 + k) * 256 + j];
    }
    Pg[idx] = ((a0 + a1) + (a2 + a3));
  }

  gridbar_full(baru, NB);   // L2 flush of init data; flags all zero after this

  // ================= GRU role (blocks 0..31) =================
  if (bid < 32) {
    float* whh = S; float* w2 = S + 6240;
    const int jb = bid * 8;
    for (int i = tid; i < 6144; i += NTHR) {
      int gg = i >> 11, r = i & 2047, jj = r >> 8, k = r & 255;
      whh[(gg * 8 + jj) * 260 + k] = W_hh[k * 768 + gg * 256 + jb + jj];
      w2 [(gg * 8 + jj) * 260 + k] = W2g [k * 768 + gg * 256 + jb + jj];
    }
    if (tid < 24) { int gg = tid / 8, jj = tid % 8;
      sb1[tid] = b_hh[gg * 256 + jb + jj];
      sb2[tid] = B2g [gg * 256 + jb + jj];
    }
    if (tid < 32) len_s[tid] = lengths[tid];
    __syncthreads();

    float* sH = S + 12480; float* sLin = S + 20800;
    float* red = S + 29120;                       // [4][1536], bank=lane
    for (int s = 0; s < kSteps; ++s) {
      int tDG = (s >= 1) ? (s < kT ? s : kT) : 0;
      int tF1 = (s >= kT + 4) ? (s - 2) : 0;
      poll(FL, tid, s, tDG, s + 1, tF1, 0);

      const float* hR = hBuf + (s & 3) * 8192;
      const float* lR = linB + (s & 3) * 8192;
      const bool useC = (s >= 1 && s < kT);
      const float4* P4 = (const float4*)(Pg + (s - 1) * 8192);
      const int* selR = selG + ((s - 1) & 3) * 32;
      float4 th[8], tl[8], tp[8];
      int tsel[8];
      #pragma unroll
      for (int u8 = 0; u8 < 8; ++u8) {
        int i4 = (tid + u8 * 256) * 4;
        th[u8] = cload4(hR + i4);
        tl[u8] = cload4(lR + i4);
      }
      if (useC) {
        #pragma unroll
        for (int u8 = 0; u8 < 8; ++u8) {
          int idx = tid + u8 * 256; int b = idx >> 6, k4 = idx & 63;
          tp[u8] = P4[b * 64 + k4];
          tsel[u8] = cload_i(&selR[b]);
        }
      }
      waitvm();
      #pragma unroll
      for (int u8 = 0; u8 < 8; ++u8) {
        int idx = tid + u8 * 256; int b = idx >> 6, k4 = idx & 63;
        *(float4*)&sH[b * 260 + k4 * 4] = th[u8];
        float cx = 0.f, cy = 0.f, cz = 0.f, cw = 0.f;
        if (useC && tsel[u8] == 0) {
          cx = 0.99f * tp[u8].x; cy = 0.99f * tp[u8].y;
          cz = 0.99f * tp[u8].z; cw = 0.99f * tp[u8].w;
        }
        float4 v;
        v.x = elu1(tl[u8].x + cx);
        v.y = elu1(tl[u8].y + cy);
        v.z = elu1(tl[u8].z + cz);
        v.w = elu1(tl[u8].w + cw);
        *(float4*)&sLin[b * 260 + k4 * 4] = v;
      }
      __syncthreads();
      const float4* sH4 = (const float4*)sH;
      const float4* sL4 = (const float4*)sLin;
      const float4* wh4 = (const float4*)whh;
      const float4* w24 = (const float4*)w2;
      const int c  = tid & 7;
      const int b4 = (tid >> 3) & 7;
      const int kq = tid >> 6;
      float acc[24];
      #pragma unroll
      for (int a = 0; a < 24; ++a) acc[a] = 0.f;
      for (int kk = 0; kk < 16; ++kk) {
        int k4 = kq * 16 + kk;
        float4 wr[6];
        #pragma unroll
        for (int gg = 0; gg < 3; ++gg) {
          wr[gg]     = wh4[(gg * 8 + c) * 65 + k4];
          wr[3 + gg] = w24[(gg * 8 + c) * 65 + k4];
        }
        #pragma unroll
        for (int bi = 0; bi < 4; ++bi) {
          int b = bi * 8 + b4;
          float4 h4 = sH4[b * 65 + k4];
          float4 l4 = sL4[b * 65 + k4];
          #pragma unroll
          for (int gg = 0; gg < 3; ++gg) {
            float4 w = wr[gg];
            acc[bi * 6 + gg]     += h4.x * w.x + h4.y * w.y + h4.z * w.z + h4.w * w.w;
            w = wr[3 + gg];
            acc[bi * 6 + 3 + gg] += l4.x * w.x + l4.y * w.y + l4.z * w.z + l4.w * w.w;
          }
        }
      }
      #pragma unroll
      for (int bi = 0; bi < 4; ++bi)
        #pragma unroll
        for (int rr = 0; rr < 6; ++rr)
          red[kq * 1536 + rr * 256 + (bi * 8 + b4) * 8 + c] = acc[bi * 6 + rr];
      __syncthreads();
      {
        int b = tid >> 3, cc = tid & 7, jg = bid * 8 + cc;
        int lo = b * 8 + cc;
        float dots[6];
        #pragma unroll
        for (int rr = 0; rr < 6; ++rr)
          dots[rr] = (red[rr * 256 + lo] + red[1536 + rr * 256 + lo]) +
                     (red[3072 + rr * 256 + lo] + red[4608 + rr * 256 + lo]);
        float ghr = dots[0] + sb1[cc];
        float ghz = dots[1] + sb1[8 + cc];
        float ghn = dots[2] + sb1[16 + cc];
        float gir = dots[3] + sb2[cc];
        float giz = dots[4] + sb2[8 + cc];
        float gin = dots[5] + sb2[16 + cc];
        float r = 1.f / (1.f + expf(-(gir + ghr)));
        float z = 1.f / (1.f + expf(-(giz + ghz)));
        float n = tanhf(gin + r * ghn);
        float hold = sH[b * 260 + jg];
        float nh = (1.f - z) * n + z * hold;
        float hv = (s < kT) ? ((s < len_s[b]) ? nh : hold) : nh;
        cstore(&hBuf[((s + 1) & 3) * 8192 + b * 256 + jg], hv);
      }
      setflag(FL, tid, bid, s + 1);
    }
  }
  // ================= E1 role (blocks 32..63) =================
  else if (bid < 64) {
    float* we1 = S;
    const int jb = (bid - 32) * 8;
    for (int i = tid; i < 1024; i += NTHR) {
      int jj = i >> 7, k = i & 127;
      we1[jj * 132 + k] = W_e1[k * 256 + jb + jj];
    }
    if (tid < 8) sb1[tid] = b_e1[jb + tid];
    __syncthreads();

    float* sx = S + 1056; float* sm = S + 3232;
    for (int e = 0; e < kSteps; ++e) {
      int tDG = e - 1 < 0 ? 0 : (e - 1 > kT ? kT : e - 1);
      poll(FL, tid, e - 2, tDG, 0, 0, 0);

      const bool encx = (e < kT);
      float4 tm[2];
      #pragma unroll
      for (int u2 = 0; u2 < 2; ++u2) {
        int idx = tid + u2 * 256; int b = idx >> 4, k4 = idx & 15;
        tm[u2] = cload4(mem + (b * kSteps + e) * kI + k4 * 4);
      }
      waitvm();
      #pragma unroll
      for (int u2 = 0; u2 < 2; ++u2) {
        int idx = tid + u2 * 256; int b = idx >> 4, k4 = idx & 15;
        *(float4*)&sm[b * 68 + k4 * 4] = tm[u2];
        if (encx)
          *(float4*)&sx[b * 68 + k4 * 4] =
              *(const float4*)(x + (b * kT + e) * kI + k4 * 4);
      }
      __syncthreads();
      const int b = tid >> 3, jj = tid & 7;
      const float4* sx4 = (const float4*)sx;
      const float4* sm4 = (const float4*)sm;
      const float4* w4p = (const float4*)we1;
      float a0 = 0, a1 = 0, a2 = 0, a3 = 0;
      if (encx) {
        for (int k4 = 0; k4 < 16; ++k4) {
          float4 xv = sx4[b * 17 + k4], w = w4p[jj * 33 + k4];
          a0 += xv.x * w.x; a1 += xv.y * w.y; a2 += xv.z * w.z; a3 += xv.w * w.w;
        }
      }
      for (int k4 = 0; k4 < 16; ++k4) {
        float4 mv = sm4[b * 17 + k4], w = w4p[jj * 33 + 16 + k4];
        a0 += mv.x * w.x; a1 += mv.y * w.y; a2 += mv.z * w.z; a3 += mv.w * w.w;
      }
      cstore(&linB[(e & 3) * 8192 + b * 256 + jb + jj],
             ((a0 + a1) + (a2 + a3)) + sb1[jj]);
      __syncthreads();
      setflag(FL, tid, 33 + (bid - 32), e + 1);
    }
  }
  // ================= F1 role (blocks 64..79) =================
  else if (bid < 80) {
    float* wf1 = S;
    const int jb = (bid - 64) * 16;
    for (int i = tid; i < 4096; i += NTHR) {
      int jj = i >> 8, k = i & 255;
      wf1[jj * 260 + k] = W_f1[k * 256 + jb + jj];
    }
    if (tid < 16) sb1[tid] = b_f1[jb + tid];
    __syncthreads();

    float* sHf = S + 4160; float* red = S + 12480; // [8][512]
    for (int s = kT + 1; s <= kSteps; ++s) {
      int tF2 = (s >= kT + 5) ? (s - 2) : 0;
      poll(FL, tid, s, 0, 0, 0, tF2);

      const float* hR = hBuf + (s & 3) * 8192;
      float4 th[8];
      #pragma unroll
      for (int u8 = 0; u8 < 8; ++u8) th[u8] = cload4(hR + (tid + u8 * 256) * 4);
      waitvm();
      #pragma unroll
      for (int u8 = 0; u8 < 8; ++u8) {
        int idx = tid + u8 * 256; int b = idx >> 6, k4 = idx & 63;
        *(float4*)&sHf[b * 260 + k4 * 4] = th[u8];
      }
      __syncthreads();
      const float4* sH4 = (const float4*)sHf;
      const float4* w4p = (const float4*)wf1;
      const int cq = tid & 3, b4 = (tid >> 2) & 7, kq = tid >> 5;
      float acc[16];
      #pragma unroll
      for (int a = 0; a < 16; ++a) acc[a] = 0.f;
      for (int kk = 0; kk < 8; ++kk) {
        int k4 = kq * 8 + kk;
        float4 wr[4];
        #pragma unroll
        for (int ci = 0; ci < 4; ++ci) wr[ci] = w4p[(cq * 4 + ci) * 65 + k4];
        #pragma unroll
        for (int bi = 0; bi < 4; ++bi) {
          float4 h4 = sH4[(bi * 8 + b4) * 65 + k4];
          #pragma unroll
          for (int ci = 0; ci < 4; ++ci) {
            float4 w = wr[ci];
            acc[bi * 4 + ci] += h4.x * w.x + h4.y * w.y + h4.z * w.z + h4.w * w.w;
          }
        }
      }
      #pragma unroll
      for (int bi = 0; bi < 4; ++bi)
        #pragma unroll
        for (int ci = 0; ci < 4; ++ci)
          red[kq * 512 + (bi * 4 + ci) * 32 + cq * 8 + b4] = acc[bi * 4 + ci];
      __syncthreads();
      #pragma unroll
      for (int u2 = 0; u2 < 2; ++u2) {
        int o = tid * 2 + u2; int b = o >> 4, col = o & 15;
        int gg = ((b >> 3) * 4 + (col & 3)) * 32 + (col >> 2) * 8 + (b & 7);
        float v = 0.f;
        #pragma unroll
        for (int kq2 = 0; kq2 < 8; ++kq2) v += red[kq2 * 512 + gg];
        v += sb1[col];
        cstore(&o1B[(s & 3) * 8192 + b * 256 + (bid - 64) * 16 + col],
               v > 0.f ? v : 0.f);
      }
      __syncthreads();
      setflag(FL, tid, 65 + (bid - 64), s + 1);
    }
  }
  // ================= F2 role (blocks 80..87) =================
  else if (bid < 88) {
    float* wf2 = S;
    const int cb = (bid - 80) * 8;
    for (int i = tid; i < 2048; i += NTHR) {
      int cc = i >> 8, k = i & 255;
      wf2[cc * 260 + k] = W_f2[k * 64 + cb + cc];
    }
    if (tid < 8) sb2[tid] = b_f2[cb + tid];
    __syncthreads();

    float* sO = S + 2080; float* red = S + 10400;  // [4][256]
    for (int s = kT + 2; s <= kSteps + 1; ++s) {
      poll(FL, tid, 0, 0, 0, s, 0);

      const float* oR = o1B + ((s - 1) & 3) * 8192;
      float4 to[8];
      #pragma unroll
      for (int u8 = 0; u8 < 8; ++u8) to[u8] = cload4(oR + (tid + u8 * 256) * 4);
      waitvm();
      #pragma unroll
      for (int u8 = 0; u8 < 8; ++u8) {
        int idx = tid + u8 * 256; int b = idx >> 6, k4 = idx & 63;
        *(float4*)&sO[b * 260 + k4 * 4] = to[u8];
      }
      __syncthreads();
      const float4* sO4 = (const float4*)sO;
      const float4* w4p = (const float4*)wf2;
      const int c = tid & 7, b4 = (tid >> 3) & 7, kq = tid >> 6;
      float acc[4] = {0.f, 0.f, 0.f, 0.f};
      for (int kk = 0; kk < 16; ++kk) {
        int k4 = kq * 16 + kk;
        float4 w = w4p[c * 65 + k4];
        #pragma unroll
        for (int bi = 0; bi < 4; ++bi) {
          float4 o4 = sO4[(bi * 8 + b4) * 65 + k4];
          acc[bi] += o4.x * w.x + o4.y * w.y + o4.z * w.z + o4.w * w.w;
        }
      }
      #pragma unroll
      for (int bi = 0; bi < 4; ++bi)
        red[kq * 256 + bi * 64 + b4 * 8 + c] = acc[bi];
      __syncthreads();
      { int b = tid >> 3, col = tid & 7;
        int gg = (b >> 3) * 64 + (b & 7) * 8 + col;
        float v = (red[gg] + red[256 + gg]) + (red[512 + gg] + red[768 + gg]);
        out[(b * kOut + (s - 2 - kT)) * kC + (bid - 80) * 8 + col] =
            v + sb2[col];
      }
      __syncthreads();
      setflag(FL, tid, 81 + (bid - 80), s + 1);
    }
  }
  // ================= DG role (block 88) =================
  else {
    float* wdg1 = S; float* wdg2 = S + 10368;
    for (int i = tid; i < 10240; i += NTHR) {
      int j = i / 320, k = i % 320;
      wdg1[j * 324 + k] = W_dg1[k * 32 + j];
    }
    for (int i = tid; i < 1024; i += NTHR) wdg2[i] = W_dg2[i];
    if (tid < 32) { sb1[tid] = b_dg1[tid]; sb2[tid] = b_dg2[tid];
                    dec_sh[tid] = powf(0.99f, (float)(tid + 1)); }
    __syncthreads();

    float* sXH = S + 11392;                       // [32][324]
    float* red = S + 21760;                       // [4][1024]
    float* l1s = S + 25856;                       // [32][36]
    for (int s = 0; s < kT; ++s) {
      poll(FL, tid, s, 0, 0, 0, 0);

      const float* hR = hBuf + (s & 3) * 8192;
      float4 th[8];
      #pragma unroll
      for (int u8 = 0; u8 < 8; ++u8) th[u8] = cload4(hR + (tid + u8 * 256) * 4);
      waitvm();
      #pragma unroll
      for (int u8 = 0; u8 < 8; ++u8) {
        int idx = tid + u8 * 256; int b = idx >> 6, k4 = idx & 63;
        *(float4*)&sXH[b * 324 + 64 + k4 * 4] = th[u8];
      }
      #pragma unroll
      for (int u2 = 0; u2 < 2; ++u2) {
        int idx = tid + u2 * 256; int b = idx >> 4, k4 = idx & 15;
        *(float4*)&sXH[b * 324 + k4 * 4] =
            *(const float4*)(x + (b * kT + s) * kI + k4 * 4);
      }
      __syncthreads();
      {
        const float4* sA4 = (const float4*)sXH;
        const float4* wd4 = (const float4*)wdg1;
        const int cq = tid & 7, b4 = (tid >> 3) & 7, kq = tid >> 6;
        float acc[16];
        #pragma unroll
        for (int a = 0; a < 16; ++a) acc[a] = 0.f;
        for (int kk = 0; kk < 20; ++kk) {
          int k4 = kq * 20 + kk;
          float4 wr[4];
          #pragma unroll
          for (int ci = 0; ci < 4; ++ci) wr[ci] = wd4[(cq * 4 + ci) * 81 + k4];
          #pragma unroll
          for (int bi = 0; bi < 4; ++bi) {
            float4 a4 = sA4[(bi * 8 + b4) * 81 + k4];
            #pragma unroll
            for (int ci = 0; ci < 4; ++ci) {
              float4 w = wr[ci];
              acc[bi * 4 + ci] += a4.x * w.x + a4.y * w.y + a4.z * w.z + a4.w * w.w;
            }
          }
        }
        #pragma unroll
        for (int bi = 0; bi < 4; ++bi)
          #pragma unroll
          for (int ci = 0; ci < 4; ++ci)
            red[kq * 1024 + (ci * 4 + bi) * 64 + cq * 8 + b4] = acc[bi * 4 + ci];
        __syncthreads();
        #pragma unroll
        for (int u4 = 0; u4 < 4; ++u4) {
          int o = tid * 4 + u4; int b = o >> 5, col = o & 31;
          int ci = col & 3, cq2 = col >> 2, bi = b >> 3, b42 = b & 7;
          int f = (ci * 4 + bi) * 64 + cq2 * 8 + b42;
          float v = (red[f] + red[1024 + f]) + (red[2048 + f] + red[3072 + f]);
          l1s[b * 36 + col] = elu1(v + sb1[col]);
        }
      }
      __syncthreads();
      for (int it = 0; it < 4; ++it) {            // dg2 + gumbel
        int i = tid + it * 256; int b = i >> 5, j = i & 31;
        float sv = sb2[j];
        for (int k = 0; k < 32; ++k) sv += l1s[b * 36 + k] * wdg2[k * 32 + j];
        lgarr[b * 33 + j] = sv + g[(s * 32 + b) * 32 + j];
      }
      __syncthreads();
      if (tid < 32) {
        float best = lgarr[tid * 33]; int bi = 0;
        for (int j = 1; j < 32; ++j) {
          float v = lgarr[tid * 33 + j];
          if (v > best) { best = v; bi = j; }
        }
        sel[tid] = bi;
      }
      __syncthreads();
      if (tid < 32) cstore_i(&selG[(s & 3) * 32 + tid], sel[tid]);
      for (int it = 0; it < 8; ++it) {            // mem events, d >= 1
        int i = tid + it * 256; int b = i >> 6, ii = i & 63;
        int d = sel[b];
        if (d > 0) {
          int c = s + 1 + d, e = -1;
          if (c < kT) e = c;
          else { int rr = c - kT - 1;
                 if (rr >= 0 && !(rr & 1)) { int kk = rr >> 1; if (kk < kOut) e = kT + kk; } }
          if (e >= 0) {
            float* p = &mem[(b * kSteps + e) * kI + ii];
            cstore(p, cload(p) + sXH[b * 324 + ii] * dec_sh[d]);
          }
        }
      }
      setflag(FL, tid, 32, s + 1);
    }
  }
}

extern "C" void kernel_launch(void* const* d_in, const int* in_sizes, int n_in,
                              void* d_out, int out_size, void* d_ws, size_t ws_size,
                              hipStream_t stream) {
  (void)in_sizes; (void)n_in; (void)out_size; (void)ws_size;
  const float* x      = (const float*)d_in[0];
  const int*   lens   = (const int*)  d_in[1];
  const float* W_dg1  = (const float*)d_in[3];
  const float* b_dg1  = (const float*)d_in[4];
  const float* W_dg2  = (const float*)d_in[5];
  const float* b_dg2  = (const float*)d_in[6];
  const float* W_e1   = (const float*)d_in[7];
  const float* b_e1   = (const float*)d_in[8];
  const float* W_e2   = (const float*)d_in[9];
  const float* b_e2   = (const float*)d_in[10];
  const float* W_ih   = (const float*)d_in[11];
  const float* b_ih   = (const float*)d_in[12];
  const float* W_hh   = (const float*)d_in[13];
  const float* b_hh   = (const float*)d_in[14];
  const float* W_f1   = (const float*)d_in[15];
  const float* b_f1   = (const float*)d_in[16];
  const float* W_f2   = (const float*)d_in[17];
  const float* b_f2   = (const float*)d_in[18];

  hipMemsetAsync(d_ws, 0, WS_ZERO_BYTES, stream);
  delay_rnn<<<dim3(NB), dim3(NTHR), 0, stream>>>(
      x, lens, W_dg1, b_dg1, W_dg2, b_dg2, W_e1, b_e1, W_e2, b_e2,
      W_ih, b_ih, W_hh, b_hh, W_f1, b_f1, W_f2, b_f2,
      (float*)d_out, (float*)d_ws);
}